// Round 16
// baseline (140.914 us; speedup 1.0000x reference)
//
#include <hip/hip_runtime.h>

#define N_NODES 50000
#define N_EDGES 800000
#define F1 64
#define F2 16
#define NBINS 196      // ceil(50000/256) node bins
#define BIN_SHIFT 8    // 256 nodes per bin
#define EPB 4096       // edges per binscatter block (20.5KB smem -> 7 blocks/CU,
                       // 196+1563=1759 blocks fit ONE round; first clean EPB test)
#define NSB ((N_EDGES + EPB - 1) / EPB)   // 196 scatter blocks
#define TBW 200        // table row stride (197 used; 196*200=39200 <= 40960 slot)
#define STAGE_MAX 6144 // max edges per bin (mean 4082, sigma ~64)
#define G1_ROWS 32     // rows per gemm1 block (4 waves x 8 rows) — r13 proven
#define G1_NB ((N_NODES + G1_ROWS - 1) / G1_ROWS)  // 1563

typedef _Float16 half_t;
typedef __attribute__((ext_vector_type(8))) _Float16 half8;  // 16 B
typedef __attribute__((ext_vector_type(4))) _Float16 half4;  // 8 B

// wave-level inclusive scan (integer, exact): 6 shfl_up steps, no barriers
__device__ __forceinline__ int wscan(int v, int lane) {
#pragma unroll
    for (int d = 1; d < 64; d <<= 1) {
        int u = __shfl_up(v, d);
        if (lane >= d) v += u;
    }
    return v;
}

// ============ launch 1: binscatter (blocks 0..NSB-1) || gemm1 (rest) ============
// r13 structure; ONLY change: EPB 8192->4096 (LDS 36->20.5KB, one block round).
__global__ void __launch_bounds__(256) k_bs_gemm1(
        const int* __restrict__ src, const int* __restrict__ dst,
        unsigned* __restrict__ pairs, int* __restrict__ table,
        const float* __restrict__ x, const float* __restrict__ W1,
        half_t* __restrict__ h0h) {
    __shared__ int smem[1024 + EPB];   // 20.5 KB, shared by both branches
    int t = threadIdx.x;               // 256

    if (blockIdx.x < NSB) {
        int* hist    = smem;                     // 196 (256 span)
        int* loff    = smem + 256;               // 197
        int* lcur    = smem + 512;               // 196
        int* wtot    = smem + 768;               // 4 (wave totals)
        unsigned* stage = (unsigned*)(smem + 1024);  // EPB, 16B-aligned
        int blk = blockIdx.x;
        int e0 = blk * EPB;
        int eend = min(e0 + EPB, N_EDGES);
        int n = eend - e0;                       // 4096 or 1280 (both %4==0)

        for (int i = t; i < NBINS; i += 256) hist[i] = 0;
        __syncthreads();
        for (int e = e0 + 4 * t; e < eend; e += 1024) {   // int4 histogram pass
            int4 d4 = *(const int4*)(dst + e);
            atomicAdd(&hist[d4.x >> BIN_SHIFT], 1);
            atomicAdd(&hist[d4.y >> BIN_SHIFT], 1);
            atomicAdd(&hist[d4.z >> BIN_SHIFT], 1);
            atomicAdd(&hist[d4.w >> BIN_SHIFT], 1);
        }
        __syncthreads();
        // exclusive prefix of hist via wave shfl scan (1 barrier total)
        int v = (t < NBINS) ? hist[t] : 0;
        int bl = t & 63, bw = t >> 6;            // 4 waves
        int sc = wscan(v, bl);
        if (bl == 63) wtot[bw] = sc;
        __syncthreads();
        int pre = 0;
#pragma unroll
        for (int w = 0; w < 3; ++w) if (w < bw) pre += wtot[w];
        int excl = sc + pre - v;
        if (t < NBINS) { loff[t] = excl; lcur[t] = excl; }
        if (t == 0) loff[NBINS] = n;
        __syncthreads();
        for (int e = e0 + 4 * t; e < eend; e += 1024) {   // int4 scatter pass
            int4 d4 = *(const int4*)(dst + e);
            int4 s4 = *(const int4*)(src + e);
            int p;
            p = atomicAdd(&lcur[d4.x >> BIN_SHIFT], 1);
            stage[p] = (unsigned)s4.x | ((unsigned)(d4.x & 255) << 16);
            p = atomicAdd(&lcur[d4.y >> BIN_SHIFT], 1);
            stage[p] = (unsigned)s4.y | ((unsigned)(d4.y & 255) << 16);
            p = atomicAdd(&lcur[d4.z >> BIN_SHIFT], 1);
            stage[p] = (unsigned)s4.z | ((unsigned)(d4.z & 255) << 16);
            p = atomicAdd(&lcur[d4.w >> BIN_SHIFT], 1);
            stage[p] = (unsigned)s4.w | ((unsigned)(d4.w & 255) << 16);
        }
        if (t <= NBINS) table[blk * TBW + t] = loff[t];
        __syncthreads();
        for (int i = 4 * t; i < n; i += 1024)             // uint4 coalesced flush
            *(uint4*)(pairs + e0 + i) = *(const uint4*)(stage + i);
    } else {
        // gemm1: h0 = fp16(x @ W1), 8 rows/wave in registers, readlane broadcast.
        float* Ws = (float*)smem;        // 4096 words
        int bid = blockIdx.x - NSB;
        int lane = t & 63, wid = t >> 6;
        for (int i = t; i < F1 * F1; i += 256) Ws[i] = W1[i];
        int row0 = bid * G1_ROWS + wid * 8;
        float xv[8], acc[8];
#pragma unroll
        for (int r = 0; r < 8; ++r) {
            int row = row0 + r;
            xv[r] = (row < N_NODES) ? x[row * F1 + lane] : 0.f;
            acc[r] = 0.f;
        }
        __syncthreads();
#pragma unroll
        for (int k = 0; k < F1; ++k) {
            float w = Ws[k * F1 + lane];   // 1 LDS read per k, reused x8
#pragma unroll
            for (int r = 0; r < 8; ++r) {
                float xs = __int_as_float(
                    __builtin_amdgcn_readlane(__float_as_int(xv[r]), k));
                acc[r] = fmaf(xs, w, acc[r]);
            }
        }
#pragma unroll
        for (int r = 0; r < 8; ++r) {
            int row = row0 + r;
            if (row < N_NODES) h0h[row * F1 + lane] = (half_t)acc[r];
        }
    }
}

// ============ launch 2: binsort, 1024 thr — wave-shfl scans (r13-proven form) =======
__global__ void __launch_bounds__(1024) k_binsort(
        const int* __restrict__ table, const unsigned* __restrict__ pairs,
        float* __restrict__ dinv, int* __restrict__ node_start,
        unsigned short* __restrict__ csr) {
    __shared__ int segoff[NSB], segcnt[NSB], segdst[NSB];
    __shared__ int hist[256], lcur[256];
    __shared__ int wtc[4], wts[4], wtd[4];        // wave totals (first 4 waves)
    __shared__ unsigned stage[STAGE_MAX];         // 24 KB
    __shared__ unsigned short sorted[STAGE_MAX];  // 12 KB
    int t = threadIdx.x, b = blockIdx.x;
    int lane = t & 63, w4 = t >> 6;

    if (t < 256) hist[t] = 0;

    // segment descriptors + dual wave-scan: counts -> stage dests, col-sum -> bin_start
    int c = 0, cs = 0;
    if (t < NSB) {
        int o = table[t * TBW + b];
        segoff[t] = o;
        cs = o;
        c = table[t * TBW + b + 1] - o;
        segcnt[t] = c;
    }
    int sc_c = wscan(c, lane);         // zero for t >= NSB; waves 4-15 scan zeros
    int sc_s = wscan(cs, lane);
    if (t < 256 && lane == 63) { wtc[w4] = sc_c; wts[w4] = sc_s; }
    __syncthreads();
    int pre_c = 0;
    if (t < 256) {
#pragma unroll
        for (int w = 0; w < 3; ++w) if (w < w4) pre_c += wtc[w];
    }
    if (t < NSB) segdst[t] = sc_c + pre_c - c;
    int n      = wtc[0] + wtc[1] + wtc[2] + wtc[3];   // this bin's edge count
    int bstart = wts[0] + wts[1] + wts[2] + wts[3];   // global exclusive bin start
    __syncthreads();                   // publish segdst before gather

    // gather the 196 segments into LDS — 16-lane groups (~21 edges/segment)
    int grp = t >> 4, gl = t & 15;     // 64 groups x 16 lanes
    for (int k = grp; k < NSB; k += 64) {
        int sc = segcnt[k], base = k * EPB + segoff[k], sd = segdst[k];
        for (int i = gl; i < sc; i += 16) stage[sd + i] = pairs[base + i];
    }
    __syncthreads();

    // node histogram == degree
    for (int i = t; i < n; i += 1024) atomicAdd(&hist[stage[i] >> 16], 1);
    __syncthreads();

    int lo = b << BIN_SHIFT;
    int nb = min(256, N_NODES - lo);
    int dg = (t < 256) ? hist[t] : 0;
    int sc_d = wscan(dg, lane);
    if (t < 256 && lane == 63) wtd[w4] = sc_d;
    __syncthreads();
    if (t < 256) {
        int pr = sc_d - dg;            // exclusive node prefix within bin
#pragma unroll
        for (int w = 0; w < 3; ++w) if (w < w4) pr += wtd[w];
        lcur[t] = pr;
        if (t < nb) {
            dinv[lo + t] = rsqrtf(1.0f + (float)dg);   // +1 self-loop
            node_start[lo + t] = bstart + pr;
        }
    }
    if (b == NBINS - 1 && t == 0) node_start[N_NODES] = N_EDGES;
    __syncthreads();

    // counting-sort scatter in LDS, coalesced flush
    for (int i = t; i < n; i += 1024) {
        unsigned p = stage[i];
        int pos = atomicAdd(&lcur[p >> 16], 1);
        sorted[pos] = (unsigned short)(p & 0xFFFF);
    }
    __syncthreads();
    for (int i = t; i < n; i += 1024) csr[bstart + i] = sorted[i];
}

// ============ launch 3: layer-1 gather + W2 — TWO NODES PER WAVE (r12-proven) ======
__global__ void __launch_bounds__(256) k_gather1f(
        const int* __restrict__ node_start, const unsigned short* __restrict__ csr,
        const float* __restrict__ dinv, const half8* __restrict__ h08,
        const float* __restrict__ b1, const float* __restrict__ W2,
        half_t* __restrict__ h1h) {
    int t = threadIdx.x;               // 256 = 4 waves, TWO nodes per wave
    int lane = t & 63, wid = t >> 6;
    int half = lane >> 5;              // node-half within wave
    int s = lane & 31;                 // sublane within half
    int j = s >> 3, f = s & 7;         // 4 edge-groups x 16B slice (128 B row)
    int g = s >> 4, c = s & 15;        // matmul: 2 k-groups x 16 output cols

    int d = blockIdx.x * 8 + wid * 2 + half;
    int start = node_start[d], end = node_start[d + 1];   // issue early

    float w2r[32];
#pragma unroll
    for (int kk = 0; kk < 32; ++kk) w2r[kk] = W2[(g * 32 + kk) * 16 + c];
    const float4* b14 = (const float4*)b1;
    float4 bA = b14[f * 2], bB = b14[f * 2 + 1];          // b1[8f..8f+7]

    float acc[8] = {0.f, 0.f, 0.f, 0.f, 0.f, 0.f, 0.f, 0.f};
    int i = start + j;
    for (; i + 4 < end; i += 8) {      // 2 chains, 8 edges/half/iter
        int s0 = csr[i], s1 = csr[i + 4];
        float w0 = dinv[s0], w1 = dinv[s1];
        half8 v0 = h08[s0 * 8 + f], v1 = h08[s1 * 8 + f];
#pragma unroll
        for (int q = 0; q < 8; ++q)
            acc[q] += w0 * (float)v0[q] + w1 * (float)v1[q];
    }
    if (i < end) {
        int sA = csr[i];
        float w = dinv[sA];
        half8 v = h08[sA * 8 + f];
#pragma unroll
        for (int q = 0; q < 8; ++q) acc[q] += w * (float)v[q];
    }
    // reduce across the 4 edge-groups (masks 8,16 stay inside the 32-lane half)
#pragma unroll
    for (int m = 8; m <= 16; m <<= 1)
#pragma unroll
        for (int q = 0; q < 8; ++q) acc[q] += __shfl_xor(acc[q], m);

    // epilogue per lane (value depends only on f within the half)
    float dd = dinv[d];
    half8 sv = h08[d * 8 + f];
    float r[8];
    {
        const float* ba = (const float*)&bA;
        const float* bb = (const float*)&bB;
#pragma unroll
        for (int q = 0; q < 8; ++q) {
            float bq = (q < 4) ? ba[q] : bb[q - 4];
            r[q] = fmaxf(dd * (acc[q] + dd * (float)sv[q]) + bq, 0.f);
        }
    }

    // 64 -> 16 matmul via half-local shfl row exchange (sources = lanes half*32+0..7)
    float p = 0.f;
#pragma unroll
    for (int kk = 0; kk < 32; ++kk) {
        int srcf = 4 * g + (kk >> 3);          // f-class of row element g*32+kk
        p += __shfl(r[kk & 7], (lane & 32) | srcf) * w2r[kk];
    }
    p += __shfl_xor(p, 16);                    // combine the 2 k-groups (in-half)
    if (g == 0) h1h[d * F2 + c] = (half_t)(dd * p);   // pre-scaled for gather2
}

// ============ launch 4: layer-2 gather — 4 nodes/wave (r11-proven) ============
__global__ void __launch_bounds__(256) k_gather2(
        const int* __restrict__ node_start, const unsigned short* __restrict__ csr,
        const float* __restrict__ dinv, const half4* __restrict__ h14,
        const float4* __restrict__ b24, float4* __restrict__ out4) {
    int t = threadIdx.x;               // 256 = 16 node-groups of 16 lanes
    int s = t & 15;                    // sublane within node-group
    int j = s >> 2, f = s & 3;         // 4 edge-groups x 8B slice (32 B row)
    int d = blockIdx.x * 16 + (t >> 4);
    int start = node_start[d], end = node_start[d + 1];
    float acc[4] = {0.f, 0.f, 0.f, 0.f};
    int i = start + j;
    for (; i + 4 < end; i += 8) {      // 2 chains, 8 edges/group/iter
        int s0 = csr[i], s1 = csr[i + 4];
        half4 v0 = h14[s0 * 4 + f], v1 = h14[s1 * 4 + f];
#pragma unroll
        for (int q = 0; q < 4; ++q) acc[q] += (float)v0[q] + (float)v1[q];
    }
    if (i < end) {
        int sA = csr[i];
        half4 v = h14[sA * 4 + f];
#pragma unroll
        for (int q = 0; q < 4; ++q) acc[q] += (float)v[q];
    }
    // reduce across the 4 edge-groups (stays inside the 16-lane node-group)
#pragma unroll
    for (int m = 4; m <= 8; m <<= 1)
#pragma unroll
        for (int q = 0; q < 4; ++q) acc[q] += __shfl_xor(acc[q], m);

    if (j == 0) {                      // lanes f=0..3 hold the full 16-dim row
        float dd = dinv[d];
        half4 sv = h14[d * 4 + f];
        float4 bb = b24[f];
        float4 r;
        r.x = bb.x + dd * (acc[0] + (float)sv[0]);
        r.y = bb.y + dd * (acc[1] + (float)sv[1]);
        r.z = bb.z + dd * (acc[2] + (float)sv[2]);
        r.w = bb.w + dd * (acc[3] + (float)sv[3]);
        out4[d * 4 + f] = r;
    }
}

extern "C" void kernel_launch(void* const* d_in, const int* in_sizes, int n_in,
                              void* d_out, int out_size, void* d_ws, size_t ws_size,
                              hipStream_t stream) {
    const float* x  = (const float*)d_in[0];          // [50000, 64]
    const int*   ei = (const int*)d_in[1];            // [2, 800000]
    const float* W1 = (const float*)d_in[2];          // [64, 64]
    const float* b1 = (const float*)d_in[3];          // [64]
    const float* W2 = (const float*)d_in[4];          // [64, 16]
    const float* b2 = (const float*)d_in[5];          // [16]
    float* out = (float*)d_out;                       // [50000, 16]

    const int* src = ei;
    const int* dst = ei + N_EDGES;

    // ws layout (4B words) — round-0 proven footprint (~13.4 MB), DO NOT EXTEND:
    int*            table      = (int*)d_ws;                    // 196*200 = 39200 <= 40960
    float*          dinv       = (float*)d_ws + 40960;          // 50000
    int*            node_start = (int*)d_ws + 91008;            // 50001
    unsigned short* csr        = (unsigned short*)((int*)d_ws + 141056);  // 800000 u16
    unsigned*       pairs      = (unsigned*)d_ws + 541056;      // 196*4096 = 802816 <= 804000
    half_t*         h0h        = (half_t*)((int*)d_ws + 1345056);  // 3.2M fp16
    half_t*         h1h        = (half_t*)((int*)d_ws + 2945056);  // 800K fp16 (pre-scaled)

    k_bs_gemm1<<<NSB + G1_NB, 256, 0, stream>>>(src, dst, pairs, table, x, W1, h0h);
    k_binsort <<<NBINS, 1024, 0, stream>>>(table, pairs, dinv, node_start, csr);
    k_gather1f<<<N_NODES / 8, 256, 0, stream>>>(node_start, csr, dinv, (const half8*)h0h,
                                                b1, W2, h1h);
    k_gather2 <<<N_NODES / 16, 256, 0, stream>>>(node_start, csr, dinv, (const half4*)h1h,
                                                 (const float4*)b2, (float4*)out);
}

// Round 17
// 138.361 us; speedup vs baseline: 1.0185x; 1.0185x over previous
//
#include <hip/hip_runtime.h>

#define N_NODES 50000
#define N_EDGES 800000
#define F1 64
#define F2 16
#define NBINS 196      // ceil(50000/256) node bins
#define BIN_SHIFT 8    // 256 nodes per bin
#define EPB 8192       // edges per binscatter block (r13 anchor geometry)
#define NSB ((N_EDGES + EPB - 1) / EPB)   // 98 scatter blocks
#define TBW 200        // table row stride (197 used)
#define STAGE_MAX 6144 // max edges per bin (mean 4082, sigma ~64)
#define G1_ROWS 32     // rows per gemm1 block (4 waves x 8 rows) — r13 proven
#define G1_NB ((N_NODES + G1_ROWS - 1) / G1_ROWS)  // 1563

typedef _Float16 half_t;
typedef __attribute__((ext_vector_type(8))) _Float16 half8;  // 16 B
typedef __attribute__((ext_vector_type(4))) _Float16 half4;  // 8 B

// wave-level inclusive scan (integer, exact): 6 shfl_up steps, no barriers
__device__ __forceinline__ int wscan(int v, int lane) {
#pragma unroll
    for (int d = 1; d < 64; d <<= 1) {
        int u = __shfl_up(v, d);
        if (lane >= d) v += u;
    }
    return v;
}

// ============ launch 1: binscatter (blocks 0..NSB-1) || gemm1 (rest) ============
// Binscatter branch = r13 verbatim. THIS ROUND: gemm1 branch goes barrier-free +
// LDS-free — W1 column slice in 64 VGPRs (r7 playbook); arithmetic bit-identical.
__global__ void __launch_bounds__(256) k_bs_gemm1(
        const int* __restrict__ src, const int* __restrict__ dst,
        unsigned* __restrict__ pairs, int* __restrict__ table,
        const float* __restrict__ x, const float* __restrict__ W1,
        half_t* __restrict__ h0h) {
    __shared__ int smem[1024 + EPB];   // 36 KB (binscatter branch only)
    int t = threadIdx.x;               // 256

    if (blockIdx.x < NSB) {
        int* hist    = smem;                     // 196
        int* loff    = smem + 256;               // 197
        int* lcur    = smem + 512;               // 196
        int* wtot    = smem + 768;               // 4 (wave totals)
        unsigned* stage = (unsigned*)(smem + 1024);  // EPB, 16B-aligned
        int blk = blockIdx.x;
        int e0 = blk * EPB;
        int eend = min(e0 + EPB, N_EDGES);
        int n = eend - e0;                       // 8192 or 5376 (both %4==0)

        for (int i = t; i < NBINS; i += 256) hist[i] = 0;
        __syncthreads();
        for (int e = e0 + 4 * t; e < eend; e += 1024) {   // int4 histogram pass
            int4 d4 = *(const int4*)(dst + e);
            atomicAdd(&hist[d4.x >> BIN_SHIFT], 1);
            atomicAdd(&hist[d4.y >> BIN_SHIFT], 1);
            atomicAdd(&hist[d4.z >> BIN_SHIFT], 1);
            atomicAdd(&hist[d4.w >> BIN_SHIFT], 1);
        }
        __syncthreads();
        // exclusive prefix of hist via wave shfl scan (1 barrier total)
        int v = (t < NBINS) ? hist[t] : 0;
        int bl = t & 63, bw = t >> 6;            // 4 waves
        int sc = wscan(v, bl);
        if (bl == 63) wtot[bw] = sc;
        __syncthreads();
        int pre = 0;
#pragma unroll
        for (int w = 0; w < 3; ++w) if (w < bw) pre += wtot[w];
        int excl = sc + pre - v;
        if (t < NBINS) { loff[t] = excl; lcur[t] = excl; }
        if (t == 0) loff[NBINS] = n;
        __syncthreads();
        for (int e = e0 + 4 * t; e < eend; e += 1024) {   // int4 scatter pass
            int4 d4 = *(const int4*)(dst + e);
            int4 s4 = *(const int4*)(src + e);
            int p;
            p = atomicAdd(&lcur[d4.x >> BIN_SHIFT], 1);
            stage[p] = (unsigned)s4.x | ((unsigned)(d4.x & 255) << 16);
            p = atomicAdd(&lcur[d4.y >> BIN_SHIFT], 1);
            stage[p] = (unsigned)s4.y | ((unsigned)(d4.y & 255) << 16);
            p = atomicAdd(&lcur[d4.z >> BIN_SHIFT], 1);
            stage[p] = (unsigned)s4.z | ((unsigned)(d4.z & 255) << 16);
            p = atomicAdd(&lcur[d4.w >> BIN_SHIFT], 1);
            stage[p] = (unsigned)s4.w | ((unsigned)(d4.w & 255) << 16);
        }
        if (t <= NBINS) table[blk * TBW + t] = loff[t];
        __syncthreads();
        for (int i = 4 * t; i < n; i += 1024)             // uint4 coalesced flush
            *(uint4*)(pairs + e0 + i) = *(const uint4*)(stage + i);
    } else {
        // gemm1: h0 = fp16(x @ W1), 8 rows/wave, readlane broadcast.
        // BARRIER-FREE: W1 column slice in 64 VGPRs (no LDS stage, no coupling).
        int bid = blockIdx.x - NSB;
        int lane = t & 63, wid = t >> 6;
        int row0 = bid * G1_ROWS + wid * 8;
        float w1r[64];
#pragma unroll
        for (int k = 0; k < F1; ++k) w1r[k] = W1[k * F1 + lane];  // coalesced, L2-hot
        float xv[8], acc[8];
#pragma unroll
        for (int r = 0; r < 8; ++r) {
            int row = row0 + r;
            xv[r] = (row < N_NODES) ? x[row * F1 + lane] : 0.f;
            acc[r] = 0.f;
        }
#pragma unroll
        for (int k = 0; k < F1; ++k) {
#pragma unroll
            for (int r = 0; r < 8; ++r) {
                float xs = __int_as_float(
                    __builtin_amdgcn_readlane(__float_as_int(xv[r]), k));
                acc[r] = fmaf(xs, w1r[k], acc[r]);   // same op order as LDS version
            }
        }
#pragma unroll
        for (int r = 0; r < 8; ++r) {
            int row = row0 + r;
            if (row < N_NODES) h0h[row * F1 + lane] = (half_t)acc[r];
        }
    }
}

// ============ launch 2: binsort, 1024 thr — wave-shfl scans (r13 verbatim) ==========
__global__ void __launch_bounds__(1024) k_binsort(
        const int* __restrict__ table, const unsigned* __restrict__ pairs,
        float* __restrict__ dinv, int* __restrict__ node_start,
        unsigned short* __restrict__ csr) {
    __shared__ int segoff[NSB], segcnt[NSB], segdst[NSB];
    __shared__ int hist[256], lcur[256];
    __shared__ int wtc[4], wts[4], wtd[4];        // wave totals (first 4 waves)
    __shared__ unsigned stage[STAGE_MAX];         // 24 KB
    __shared__ unsigned short sorted[STAGE_MAX];  // 12 KB
    int t = threadIdx.x, b = blockIdx.x;
    int lane = t & 63, w4 = t >> 6;

    if (t < 256) hist[t] = 0;

    // segment descriptors + dual wave-scan: counts -> stage dests, col-sum -> bin_start
    int c = 0, cs = 0;
    if (t < NSB) {
        int o = table[t * TBW + b];
        segoff[t] = o;
        cs = o;
        c = table[t * TBW + b + 1] - o;
        segcnt[t] = c;
    }
    int sc_c = wscan(c, lane);         // zero for t >= NSB; waves 4-15 scan zeros
    int sc_s = wscan(cs, lane);
    if (t < 256 && lane == 63) { wtc[w4] = sc_c; wts[w4] = sc_s; }
    __syncthreads();
    int pre_c = 0;
    if (t < 256) {
#pragma unroll
        for (int w = 0; w < 3; ++w) if (w < w4) pre_c += wtc[w];
    }
    if (t < NSB) segdst[t] = sc_c + pre_c - c;
    int n      = wtc[0] + wtc[1] + wtc[2] + wtc[3];   // this bin's edge count
    int bstart = wts[0] + wts[1] + wts[2] + wts[3];   // global exclusive bin start
    __syncthreads();                   // publish segdst before gather

    // gather the NSB segments into LDS — 16-lane groups (segments avg ~42 edges)
    int grp = t >> 4, gl = t & 15;     // 64 groups x 16 lanes
    for (int k = grp; k < NSB; k += 64) {
        int sc = segcnt[k], base = k * EPB + segoff[k], sd = segdst[k];
        for (int i = gl; i < sc; i += 16) stage[sd + i] = pairs[base + i];
    }
    __syncthreads();

    // node histogram == degree
    for (int i = t; i < n; i += 1024) atomicAdd(&hist[stage[i] >> 16], 1);
    __syncthreads();

    int lo = b << BIN_SHIFT;
    int nb = min(256, N_NODES - lo);
    int dg = (t < 256) ? hist[t] : 0;
    int sc_d = wscan(dg, lane);
    if (t < 256 && lane == 63) wtd[w4] = sc_d;
    __syncthreads();
    if (t < 256) {
        int pr = sc_d - dg;            // exclusive node prefix within bin
#pragma unroll
        for (int w = 0; w < 3; ++w) if (w < w4) pr += wtd[w];
        lcur[t] = pr;
        if (t < nb) {
            dinv[lo + t] = rsqrtf(1.0f + (float)dg);   // +1 self-loop
            node_start[lo + t] = bstart + pr;
        }
    }
    if (b == NBINS - 1 && t == 0) node_start[N_NODES] = N_EDGES;
    __syncthreads();

    // counting-sort scatter in LDS, coalesced flush
    for (int i = t; i < n; i += 1024) {
        unsigned p = stage[i];
        int pos = atomicAdd(&lcur[p >> 16], 1);
        sorted[pos] = (unsigned short)(p & 0xFFFF);
    }
    __syncthreads();
    for (int i = t; i < n; i += 1024) csr[bstart + i] = sorted[i];
}

// ============ launch 3: layer-1 gather + W2 — TWO NODES PER WAVE (r12-proven) ======
__global__ void __launch_bounds__(256) k_gather1f(
        const int* __restrict__ node_start, const unsigned short* __restrict__ csr,
        const float* __restrict__ dinv, const half8* __restrict__ h08,
        const float* __restrict__ b1, const float* __restrict__ W2,
        half_t* __restrict__ h1h) {
    int t = threadIdx.x;               // 256 = 4 waves, TWO nodes per wave
    int lane = t & 63, wid = t >> 6;
    int half = lane >> 5;              // node-half within wave
    int s = lane & 31;                 // sublane within half
    int j = s >> 3, f = s & 7;         // 4 edge-groups x 16B slice (128 B row)
    int g = s >> 4, c = s & 15;        // matmul: 2 k-groups x 16 output cols

    int d = blockIdx.x * 8 + wid * 2 + half;
    int start = node_start[d], end = node_start[d + 1];   // issue early

    float w2r[32];
#pragma unroll
    for (int kk = 0; kk < 32; ++kk) w2r[kk] = W2[(g * 32 + kk) * 16 + c];
    const float4* b14 = (const float4*)b1;
    float4 bA = b14[f * 2], bB = b14[f * 2 + 1];          // b1[8f..8f+7]

    float acc[8] = {0.f, 0.f, 0.f, 0.f, 0.f, 0.f, 0.f, 0.f};
    int i = start + j;
    for (; i + 4 < end; i += 8) {      // 2 chains, 8 edges/half/iter
        int s0 = csr[i], s1 = csr[i + 4];
        float w0 = dinv[s0], w1 = dinv[s1];
        half8 v0 = h08[s0 * 8 + f], v1 = h08[s1 * 8 + f];
#pragma unroll
        for (int q = 0; q < 8; ++q)
            acc[q] += w0 * (float)v0[q] + w1 * (float)v1[q];
    }
    if (i < end) {
        int sA = csr[i];
        float w = dinv[sA];
        half8 v = h08[sA * 8 + f];
#pragma unroll
        for (int q = 0; q < 8; ++q) acc[q] += w * (float)v[q];
    }
    // reduce across the 4 edge-groups (masks 8,16 stay inside the 32-lane half)
#pragma unroll
    for (int m = 8; m <= 16; m <<= 1)
#pragma unroll
        for (int q = 0; q < 8; ++q) acc[q] += __shfl_xor(acc[q], m);

    // epilogue per lane (value depends only on f within the half)
    float dd = dinv[d];
    half8 sv = h08[d * 8 + f];
    float r[8];
    {
        const float* ba = (const float*)&bA;
        const float* bb = (const float*)&bB;
#pragma unroll
        for (int q = 0; q < 8; ++q) {
            float bq = (q < 4) ? ba[q] : bb[q - 4];
            r[q] = fmaxf(dd * (acc[q] + dd * (float)sv[q]) + bq, 0.f);
        }
    }

    // 64 -> 16 matmul via half-local shfl row exchange (sources = lanes half*32+0..7)
    float p = 0.f;
#pragma unroll
    for (int kk = 0; kk < 32; ++kk) {
        int srcf = 4 * g + (kk >> 3);          // f-class of row element g*32+kk
        p += __shfl(r[kk & 7], (lane & 32) | srcf) * w2r[kk];
    }
    p += __shfl_xor(p, 16);                    // combine the 2 k-groups (in-half)
    if (g == 0) h1h[d * F2 + c] = (half_t)(dd * p);   // pre-scaled for gather2
}

// ============ launch 4: layer-2 gather — 4 nodes/wave (r11-proven) ============
__global__ void __launch_bounds__(256) k_gather2(
        const int* __restrict__ node_start, const unsigned short* __restrict__ csr,
        const float* __restrict__ dinv, const half4* __restrict__ h14,
        const float4* __restrict__ b24, float4* __restrict__ out4) {
    int t = threadIdx.x;               // 256 = 16 node-groups of 16 lanes
    int s = t & 15;                    // sublane within node-group
    int j = s >> 2, f = s & 3;         // 4 edge-groups x 8B slice (32 B row)
    int d = blockIdx.x * 16 + (t >> 4);
    int start = node_start[d], end = node_start[d + 1];
    float acc[4] = {0.f, 0.f, 0.f, 0.f};
    int i = start + j;
    for (; i + 4 < end; i += 8) {      // 2 chains, 8 edges/group/iter
        int s0 = csr[i], s1 = csr[i + 4];
        half4 v0 = h14[s0 * 4 + f], v1 = h14[s1 * 4 + f];
#pragma unroll
        for (int q = 0; q < 4; ++q) acc[q] += (float)v0[q] + (float)v1[q];
    }
    if (i < end) {
        int sA = csr[i];
        half4 v = h14[sA * 4 + f];
#pragma unroll
        for (int q = 0; q < 4; ++q) acc[q] += (float)v[q];
    }
    // reduce across the 4 edge-groups (stays inside the 16-lane node-group)
#pragma unroll
    for (int m = 4; m <= 8; m <<= 1)
#pragma unroll
        for (int q = 0; q < 4; ++q) acc[q] += __shfl_xor(acc[q], m);

    if (j == 0) {                      // lanes f=0..3 hold the full 16-dim row
        float dd = dinv[d];
        half4 sv = h14[d * 4 + f];
        float4 bb = b24[f];
        float4 r;
        r.x = bb.x + dd * (acc[0] + (float)sv[0]);
        r.y = bb.y + dd * (acc[1] + (float)sv[1]);
        r.z = bb.z + dd * (acc[2] + (float)sv[2]);
        r.w = bb.w + dd * (acc[3] + (float)sv[3]);
        out4[d * 4 + f] = r;
    }
}

extern "C" void kernel_launch(void* const* d_in, const int* in_sizes, int n_in,
                              void* d_out, int out_size, void* d_ws, size_t ws_size,
                              hipStream_t stream) {
    const float* x  = (const float*)d_in[0];          // [50000, 64]
    const int*   ei = (const int*)d_in[1];            // [2, 800000]
    const float* W1 = (const float*)d_in[2];          // [64, 64]
    const float* b1 = (const float*)d_in[3];          // [64]
    const float* W2 = (const float*)d_in[4];          // [64, 16]
    const float* b2 = (const float*)d_in[5];          // [16]
    float* out = (float*)d_out;                       // [50000, 16]

    const int* src = ei;
    const int* dst = ei + N_EDGES;

    // ws layout (4B words) — round-0 proven footprint (~13.4 MB), DO NOT EXTEND:
    int*            table      = (int*)d_ws;                    // 98*200
    float*          dinv       = (float*)d_ws + 40960;          // 50000
    int*            node_start = (int*)d_ws + 91008;            // 50001
    unsigned short* csr        = (unsigned short*)((int*)d_ws + 141056);  // 800000 u16
    unsigned*       pairs      = (unsigned*)d_ws + 541056;      // block-segmented edges
    half_t*         h0h        = (half_t*)((int*)d_ws + 1345056);  // 3.2M fp16
    half_t*         h1h        = (half_t*)((int*)d_ws + 2945056);  // 800K fp16 (pre-scaled)

    k_bs_gemm1<<<NSB + G1_NB, 256, 0, stream>>>(src, dst, pairs, table, x, W1, h0h);
    k_binsort <<<NBINS, 1024, 0, stream>>>(table, pairs, dinv, node_start, csr);
    k_gather1f<<<N_NODES / 8, 256, 0, stream>>>(node_start, csr, dinv, (const half8*)h0h,
                                                b1, W2, h1h);
    k_gather2 <<<N_NODES / 16, 256, 0, stream>>>(node_start, csr, dinv, (const half4*)h1h,
                                                 (const float4*)b2, (float4*)out);
}

// Round 18
// 136.499 us; speedup vs baseline: 1.0323x; 1.0136x over previous
//
#include <hip/hip_runtime.h>

#define N_NODES 50000
#define N_EDGES 800000
#define F1 64
#define F2 16
#define NBINS 196      // ceil(50000/256) node bins
#define BIN_SHIFT 8    // 256 nodes per bin
#define EPB 8192       // edges per binscatter block (r13 anchor geometry)
#define NSB ((N_EDGES + EPB - 1) / EPB)   // 98 scatter blocks
#define TBW 200        // table row stride (197 used)
#define STAGE_MAX 6144 // max edges per bin (mean 4082, sigma ~64)
#define G1_ROWS 32     // rows per gemm1 block (4 waves x 8 rows) — r13 proven
#define G1_NB ((N_NODES + G1_ROWS - 1) / G1_ROWS)  // 1563

typedef _Float16 half_t;
typedef __attribute__((ext_vector_type(8))) _Float16 half8;  // 16 B
typedef __attribute__((ext_vector_type(4))) _Float16 half4;  // 8 B

// wave-level inclusive scan (integer, exact): 6 shfl_up steps, no barriers
__device__ __forceinline__ int wscan(int v, int lane) {
#pragma unroll
    for (int d = 1; d < 64; d <<= 1) {
        int u = __shfl_up(v, d);
        if (lane >= d) v += u;
    }
    return v;
}

// ============ launch 1: binscatter (blocks 0..NSB-1) || gemm1 (rest) ============
// Binscatter = r13 verbatim. THIS ROUND: gemm1 x-loads vectorized to float4
// (8 scalar dword loads/wave -> 2 float4 loads/lane, 16B/lane); readlane index
// remapped accordingly; per-acc FMA k-order unchanged -> h0h bit-identical.
__global__ void __launch_bounds__(256) k_bs_gemm1(
        const int* __restrict__ src, const int* __restrict__ dst,
        unsigned* __restrict__ pairs, int* __restrict__ table,
        const float* __restrict__ x, const float* __restrict__ W1,
        half_t* __restrict__ h0h) {
    __shared__ int smem[1024 + EPB];   // 36 KB (binscatter branch only)
    int t = threadIdx.x;               // 256

    if (blockIdx.x < NSB) {
        int* hist    = smem;                     // 196
        int* loff    = smem + 256;               // 197
        int* lcur    = smem + 512;               // 196
        int* wtot    = smem + 768;               // 4 (wave totals)
        unsigned* stage = (unsigned*)(smem + 1024);  // EPB, 16B-aligned
        int blk = blockIdx.x;
        int e0 = blk * EPB;
        int eend = min(e0 + EPB, N_EDGES);
        int n = eend - e0;                       // 8192 or 5376 (both %4==0)

        for (int i = t; i < NBINS; i += 256) hist[i] = 0;
        __syncthreads();
        for (int e = e0 + 4 * t; e < eend; e += 1024) {   // int4 histogram pass
            int4 d4 = *(const int4*)(dst + e);
            atomicAdd(&hist[d4.x >> BIN_SHIFT], 1);
            atomicAdd(&hist[d4.y >> BIN_SHIFT], 1);
            atomicAdd(&hist[d4.z >> BIN_SHIFT], 1);
            atomicAdd(&hist[d4.w >> BIN_SHIFT], 1);
        }
        __syncthreads();
        // exclusive prefix of hist via wave shfl scan (1 barrier total)
        int v = (t < NBINS) ? hist[t] : 0;
        int bl = t & 63, bw = t >> 6;            // 4 waves
        int sc = wscan(v, bl);
        if (bl == 63) wtot[bw] = sc;
        __syncthreads();
        int pre = 0;
#pragma unroll
        for (int w = 0; w < 3; ++w) if (w < bw) pre += wtot[w];
        int excl = sc + pre - v;
        if (t < NBINS) { loff[t] = excl; lcur[t] = excl; }
        if (t == 0) loff[NBINS] = n;
        __syncthreads();
        for (int e = e0 + 4 * t; e < eend; e += 1024) {   // int4 scatter pass
            int4 d4 = *(const int4*)(dst + e);
            int4 s4 = *(const int4*)(src + e);
            int p;
            p = atomicAdd(&lcur[d4.x >> BIN_SHIFT], 1);
            stage[p] = (unsigned)s4.x | ((unsigned)(d4.x & 255) << 16);
            p = atomicAdd(&lcur[d4.y >> BIN_SHIFT], 1);
            stage[p] = (unsigned)s4.y | ((unsigned)(d4.y & 255) << 16);
            p = atomicAdd(&lcur[d4.z >> BIN_SHIFT], 1);
            stage[p] = (unsigned)s4.z | ((unsigned)(d4.z & 255) << 16);
            p = atomicAdd(&lcur[d4.w >> BIN_SHIFT], 1);
            stage[p] = (unsigned)s4.w | ((unsigned)(d4.w & 255) << 16);
        }
        if (t <= NBINS) table[blk * TBW + t] = loff[t];
        __syncthreads();
        for (int i = 4 * t; i < n; i += 1024)             // uint4 coalesced flush
            *(uint4*)(pairs + e0 + i) = *(const uint4*)(stage + i);
    } else {
        // gemm1: h0 = fp16(x @ W1), 8 rows/wave, readlane broadcast, barrier-free.
        // W1 column slice in 64 VGPRs; x rows via 2 float4 loads per lane.
        int bid = blockIdx.x - NSB;
        int lane = t & 63, wid = t >> 6;
        int row0 = bid * G1_ROWS + wid * 8;
        float w1r[64];
#pragma unroll
        for (int k = 0; k < F1; ++k) w1r[k] = W1[k * F1 + lane];  // coalesced, L2-hot
        // x load: chunk rr covers rows row0+rr*4 .. +3; lane -> row row0+rr*4+(lane>>4),
        // cols (lane&15)*4 .. +3. 16B/lane, fully coalesced (1KB per wave per load).
        float4 xq[2];
#pragma unroll
        for (int rr = 0; rr < 2; ++rr) {
            int row = row0 + rr * 4 + (lane >> 4);
            xq[rr] = (row < N_NODES)
                         ? *(const float4*)(x + row * F1 + (lane & 15) * 4)
                         : float4{0.f, 0.f, 0.f, 0.f};
        }
        float acc[8];
#pragma unroll
        for (int r = 0; r < 8; ++r) acc[r] = 0.f;
#pragma unroll
        for (int k = 0; k < F1; ++k) {
#pragma unroll
            for (int r = 0; r < 8; ++r) {
                // element k of row row0+r lives in lane (r&3)*16 + (k>>2), slot k&3
                const float* xf = (const float*)&xq[r >> 2];
                float xs = __int_as_float(__builtin_amdgcn_readlane(
                    __float_as_int(xf[k & 3]), ((r & 3) << 4) | (k >> 2)));
                acc[r] = fmaf(xs, w1r[k], acc[r]);   // same k-order as before
            }
        }
#pragma unroll
        for (int r = 0; r < 8; ++r) {
            int row = row0 + r;
            if (row < N_NODES) h0h[row * F1 + lane] = (half_t)acc[r];
        }
    }
}

// ============ launch 2: binsort, 1024 thr — wave-shfl scans (r13 verbatim) ==========
__global__ void __launch_bounds__(1024) k_binsort(
        const int* __restrict__ table, const unsigned* __restrict__ pairs,
        float* __restrict__ dinv, int* __restrict__ node_start,
        unsigned short* __restrict__ csr) {
    __shared__ int segoff[NSB], segcnt[NSB], segdst[NSB];
    __shared__ int hist[256], lcur[256];
    __shared__ int wtc[4], wts[4], wtd[4];        // wave totals (first 4 waves)
    __shared__ unsigned stage[STAGE_MAX];         // 24 KB
    __shared__ unsigned short sorted[STAGE_MAX];  // 12 KB
    int t = threadIdx.x, b = blockIdx.x;
    int lane = t & 63, w4 = t >> 6;

    if (t < 256) hist[t] = 0;

    // segment descriptors + dual wave-scan: counts -> stage dests, col-sum -> bin_start
    int c = 0, cs = 0;
    if (t < NSB) {
        int o = table[t * TBW + b];
        segoff[t] = o;
        cs = o;
        c = table[t * TBW + b + 1] - o;
        segcnt[t] = c;
    }
    int sc_c = wscan(c, lane);         // zero for t >= NSB; waves 4-15 scan zeros
    int sc_s = wscan(cs, lane);
    if (t < 256 && lane == 63) { wtc[w4] = sc_c; wts[w4] = sc_s; }
    __syncthreads();
    int pre_c = 0;
    if (t < 256) {
#pragma unroll
        for (int w = 0; w < 3; ++w) if (w < w4) pre_c += wtc[w];
    }
    if (t < NSB) segdst[t] = sc_c + pre_c - c;
    int n      = wtc[0] + wtc[1] + wtc[2] + wtc[3];   // this bin's edge count
    int bstart = wts[0] + wts[1] + wts[2] + wts[3];   // global exclusive bin start
    __syncthreads();                   // publish segdst before gather

    // gather the NSB segments into LDS — 16-lane groups (segments avg ~42 edges)
    int grp = t >> 4, gl = t & 15;     // 64 groups x 16 lanes
    for (int k = grp; k < NSB; k += 64) {
        int sc = segcnt[k], base = k * EPB + segoff[k], sd = segdst[k];
        for (int i = gl; i < sc; i += 16) stage[sd + i] = pairs[base + i];
    }
    __syncthreads();

    // node histogram == degree
    for (int i = t; i < n; i += 1024) atomicAdd(&hist[stage[i] >> 16], 1);
    __syncthreads();

    int lo = b << BIN_SHIFT;
    int nb = min(256, N_NODES - lo);
    int dg = (t < 256) ? hist[t] : 0;
    int sc_d = wscan(dg, lane);
    if (t < 256 && lane == 63) wtd[w4] = sc_d;
    __syncthreads();
    if (t < 256) {
        int pr = sc_d - dg;            // exclusive node prefix within bin
#pragma unroll
        for (int w = 0; w < 3; ++w) if (w < w4) pr += wtd[w];
        lcur[t] = pr;
        if (t < nb) {
            dinv[lo + t] = rsqrtf(1.0f + (float)dg);   // +1 self-loop
            node_start[lo + t] = bstart + pr;
        }
    }
    if (b == NBINS - 1 && t == 0) node_start[N_NODES] = N_EDGES;
    __syncthreads();

    // counting-sort scatter in LDS, coalesced flush
    for (int i = t; i < n; i += 1024) {
        unsigned p = stage[i];
        int pos = atomicAdd(&lcur[p >> 16], 1);
        sorted[pos] = (unsigned short)(p & 0xFFFF);
    }
    __syncthreads();
    for (int i = t; i < n; i += 1024) csr[bstart + i] = sorted[i];
}

// ============ launch 3: layer-1 gather + W2 — TWO NODES PER WAVE (r12-proven) ======
__global__ void __launch_bounds__(256) k_gather1f(
        const int* __restrict__ node_start, const unsigned short* __restrict__ csr,
        const float* __restrict__ dinv, const half8* __restrict__ h08,
        const float* __restrict__ b1, const float* __restrict__ W2,
        half_t* __restrict__ h1h) {
    int t = threadIdx.x;               // 256 = 4 waves, TWO nodes per wave
    int lane = t & 63, wid = t >> 6;
    int half = lane >> 5;              // node-half within wave
    int s = lane & 31;                 // sublane within half
    int j = s >> 3, f = s & 7;         // 4 edge-groups x 16B slice (128 B row)
    int g = s >> 4, c = s & 15;        // matmul: 2 k-groups x 16 output cols

    int d = blockIdx.x * 8 + wid * 2 + half;
    int start = node_start[d], end = node_start[d + 1];   // issue early

    float w2r[32];
#pragma unroll
    for (int kk = 0; kk < 32; ++kk) w2r[kk] = W2[(g * 32 + kk) * 16 + c];
    const float4* b14 = (const float4*)b1;
    float4 bA = b14[f * 2], bB = b14[f * 2 + 1];          // b1[8f..8f+7]

    float acc[8] = {0.f, 0.f, 0.f, 0.f, 0.f, 0.f, 0.f, 0.f};
    int i = start + j;
    for (; i + 4 < end; i += 8) {      // 2 chains, 8 edges/half/iter
        int s0 = csr[i], s1 = csr[i + 4];
        float w0 = dinv[s0], w1 = dinv[s1];
        half8 v0 = h08[s0 * 8 + f], v1 = h08[s1 * 8 + f];
#pragma unroll
        for (int q = 0; q < 8; ++q)
            acc[q] += w0 * (float)v0[q] + w1 * (float)v1[q];
    }
    if (i < end) {
        int sA = csr[i];
        float w = dinv[sA];
        half8 v = h08[sA * 8 + f];
#pragma unroll
        for (int q = 0; q < 8; ++q) acc[q] += w * (float)v[q];
    }
    // reduce across the 4 edge-groups (masks 8,16 stay inside the 32-lane half)
#pragma unroll
    for (int m = 8; m <= 16; m <<= 1)
#pragma unroll
        for (int q = 0; q < 8; ++q) acc[q] += __shfl_xor(acc[q], m);

    // epilogue per lane (value depends only on f within the half)
    float dd = dinv[d];
    half8 sv = h08[d * 8 + f];
    float r[8];
    {
        const float* ba = (const float*)&bA;
        const float* bb = (const float*)&bB;
#pragma unroll
        for (int q = 0; q < 8; ++q) {
            float bq = (q < 4) ? ba[q] : bb[q - 4];
            r[q] = fmaxf(dd * (acc[q] + dd * (float)sv[q]) + bq, 0.f);
        }
    }

    // 64 -> 16 matmul via half-local shfl row exchange (sources = lanes half*32+0..7)
    float p = 0.f;
#pragma unroll
    for (int kk = 0; kk < 32; ++kk) {
        int srcf = 4 * g + (kk >> 3);          // f-class of row element g*32+kk
        p += __shfl(r[kk & 7], (lane & 32) | srcf) * w2r[kk];
    }
    p += __shfl_xor(p, 16);                    // combine the 2 k-groups (in-half)
    if (g == 0) h1h[d * F2 + c] = (half_t)(dd * p);   // pre-scaled for gather2
}

// ============ launch 4: layer-2 gather — 4 nodes/wave (r11-proven) ============
__global__ void __launch_bounds__(256) k_gather2(
        const int* __restrict__ node_start, const unsigned short* __restrict__ csr,
        const float* __restrict__ dinv, const half4* __restrict__ h14,
        const float4* __restrict__ b24, float4* __restrict__ out4) {
    int t = threadIdx.x;               // 256 = 16 node-groups of 16 lanes
    int s = t & 15;                    // sublane within node-group
    int j = s >> 2, f = s & 3;         // 4 edge-groups x 8B slice (32 B row)
    int d = blockIdx.x * 16 + (t >> 4);
    int start = node_start[d], end = node_start[d + 1];
    float acc[4] = {0.f, 0.f, 0.f, 0.f};
    int i = start + j;
    for (; i + 4 < end; i += 8) {      // 2 chains, 8 edges/group/iter
        int s0 = csr[i], s1 = csr[i + 4];
        half4 v0 = h14[s0 * 4 + f], v1 = h14[s1 * 4 + f];
#pragma unroll
        for (int q = 0; q < 4; ++q) acc[q] += (float)v0[q] + (float)v1[q];
    }
    if (i < end) {
        int sA = csr[i];
        half4 v = h14[sA * 4 + f];
#pragma unroll
        for (int q = 0; q < 4; ++q) acc[q] += (float)v[q];
    }
    // reduce across the 4 edge-groups (stays inside the 16-lane node-group)
#pragma unroll
    for (int m = 4; m <= 8; m <<= 1)
#pragma unroll
        for (int q = 0; q < 4; ++q) acc[q] += __shfl_xor(acc[q], m);

    if (j == 0) {                      // lanes f=0..3 hold the full 16-dim row
        float dd = dinv[d];
        half4 sv = h14[d * 4 + f];
        float4 bb = b24[f];
        float4 r;
        r.x = bb.x + dd * (acc[0] + (float)sv[0]);
        r.y = bb.y + dd * (acc[1] + (float)sv[1]);
        r.z = bb.z + dd * (acc[2] + (float)sv[2]);
        r.w = bb.w + dd * (acc[3] + (float)sv[3]);
        out4[d * 4 + f] = r;
    }
}

extern "C" void kernel_launch(void* const* d_in, const int* in_sizes, int n_in,
                              void* d_out, int out_size, void* d_ws, size_t ws_size,
                              hipStream_t stream) {
    const float* x  = (const float*)d_in[0];          // [50000, 64]
    const int*   ei = (const int*)d_in[1];            // [2, 800000]
    const float* W1 = (const float*)d_in[2];          // [64, 64]
    const float* b1 = (const float*)d_in[3];          // [64]
    const float* W2 = (const float*)d_in[4];          // [64, 16]
    const float* b2 = (const float*)d_in[5];          // [16]
    float* out = (float*)d_out;                       // [50000, 16]

    const int* src = ei;
    const int* dst = ei + N_EDGES;

    // ws layout (4B words) — round-0 proven footprint (~13.4 MB), DO NOT EXTEND:
    int*            table      = (int*)d_ws;                    // 98*200
    float*          dinv       = (float*)d_ws + 40960;          // 50000
    int*            node_start = (int*)d_ws + 91008;            // 50001
    unsigned short* csr        = (unsigned short*)((int*)d_ws + 141056);  // 800000 u16
    unsigned*       pairs      = (unsigned*)d_ws + 541056;      // block-segmented edges
    half_t*         h0h        = (half_t*)((int*)d_ws + 1345056);  // 3.2M fp16
    half_t*         h1h        = (half_t*)((int*)d_ws + 2945056);  // 800K fp16 (pre-scaled)

    k_bs_gemm1<<<NSB + G1_NB, 256, 0, stream>>>(src, dst, pairs, table, x, W1, h0h);
    k_binsort <<<NBINS, 1024, 0, stream>>>(table, pairs, dinv, node_start, csr);
    k_gather1f<<<N_NODES / 8, 256, 0, stream>>>(node_start, csr, dinv, (const half8*)h0h,
                                                b1, W2, h1h);
    k_gather2 <<<N_NODES / 16, 256, 0, stream>>>(node_start, csr, dinv, (const half4*)h1h,
                                                 (const float4*)b2, (float4*)out);
}